// Round 16
// baseline (158.693 us; speedup 1.0000x reference)
//
#include <hip/hip_runtime.h>
#include <hip/hip_bf16.h>
#include <math.h>

// Problem constants: B=8, C=64, H=256, W=256
static constexpr int kC = 64;
static constexpr int kH = 256;
static constexpr int kW = 256;
static constexpr int kPlane = kH * kW;   // 65536

typedef __attribute__((ext_vector_type(8))) short bf16x8;
typedef __attribute__((ext_vector_type(4))) float f32x4;

__device__ __forceinline__ unsigned short f2bf(float f) {
    unsigned u = __builtin_bit_cast(unsigned, f);
    u += 0x7FFFu + ((u >> 16) & 1u);     // round-to-nearest-even
    return (unsigned short)(u >> 16);
}

// Fixed stencils (same normalization as reference)
__constant__ float K_SX[9]  = {-0.125f, 0.0f, 0.125f,  -0.25f, 0.0f, 0.25f,  -0.125f, 0.0f, 0.125f};
__constant__ float K_SY[9]  = {-0.125f, -0.25f, -0.125f,  0.0f, 0.0f, 0.0f,  0.125f, 0.25f, 0.125f};
__constant__ float K_LAP[9] = {0.0f, -1.0f/6.0f, 0.0f,  -1.0f/6.0f, 4.0f/6.0f, -1.0f/6.0f,  0.0f, -1.0f/6.0f, 0.0f};
__constant__ float K_CS[9]  = {-1.0f/9.0f, -1.0f/9.0f, -1.0f/9.0f,  -1.0f/9.0f, 8.0f/9.0f, -1.0f/9.0f,  -1.0f/9.0f, -1.0f/9.0f, -1.0f/9.0f};

// ---- Kernel A+B merged: partial pool (all blocks) + att/prepack (last block) ----
// Pool body = r10-proven. Last-finished block (device-scope counter) runs the
// r10-proven att_wc body verbatim: deterministic output (fixed-order math,
// block identity irrelevant). Counter is memset to 0 each launch.
__global__ __launch_bounds__(256) void pool_att_kernel(
    const float* __restrict__ x,        // [8][64][256][256]
    const float* __restrict__ idg_w,    // [64][9]
    const float* __restrict__ van_w,    // [64][9]
    const float* __restrict__ w1,       // [16][64]
    const float* __restrict__ b1,       // [16]
    const float* __restrict__ w2,       // [384][16]
    const float* __restrict__ b2,       // [384]
    const float* __restrict__ fus_w,    // [64][64] (o,c)
    float* __restrict__ partial,        // [512][4]
    unsigned* __restrict__ counter,     // 1 (zeroed each launch)
    float* __restrict__ wc_out,         // [8][64][9]
    unsigned short* __restrict__ apk)   // [2][4][64][8] bf16 weight fragments
{
    // ---------------- pool partial (r10 body) ----------------
    const int blk = blockIdx.x;            // 0..2047
    const int bc  = blk >> 2;
    const int q   = blk & 3;
    const float4* p = (const float4*)(x + (size_t)bc * kPlane) + q * 4096 + threadIdx.x;
    float s0 = 0.f, s1 = 0.f, s2 = 0.f, s3 = 0.f;
    #pragma unroll
    for (int i = 0; i < 16; i += 4) {
        const float4 a = p[(i + 0) * 256];
        const float4 b = p[(i + 1) * 256];
        const float4 c = p[(i + 2) * 256];
        const float4 d = p[(i + 3) * 256];
        s0 += (a.x + a.y) + (a.z + a.w);
        s1 += (b.x + b.y) + (b.z + b.w);
        s2 += (c.x + c.y) + (c.z + c.w);
        s3 += (d.x + d.y) + (d.z + d.w);
    }
    float s = (s0 + s1) + (s2 + s3);
    for (int off = 32; off; off >>= 1) s += __shfl_down(s, off);
    __shared__ float red[4];
    __shared__ int slast;
    if ((threadIdx.x & 63) == 0) red[threadIdx.x >> 6] = s;
    __syncthreads();
    if (threadIdx.x == 0) {
        partial[blk] = red[0] + red[1] + red[2] + red[3];
        __threadfence();                              // release partial[blk]
        const unsigned prev = atomicAdd(counter, 1u); // device-scope
        slast = (prev == 2047u) ? 1 : 0;
    }
    __syncthreads();
    if (!slast) return;
    __threadfence();                                  // acquire all partial[]

    // ---------------- att + prepack (r10 att_wc body, verbatim) ----------------
    __shared__ float spool[512];
    __shared__ float sh[8][16];
    __shared__ float satt[8 * 384];
    const int t = threadIdx.x;

    for (int i = t; i < 512; i += 256)
        spool[i] = (partial[4 * i] + partial[4 * i + 1] + partial[4 * i + 2] + partial[4 * i + 3])
                   * (1.0f / (float)kPlane);
    __syncthreads();

    if (t < 128) {
        const int b = t >> 4, j = t & 15;
        float acc = b1[j];
        const float* wr = w1 + j * 64;
        const float* pr = spool + b * 64;
        #pragma unroll 8
        for (int c = 0; c < 64; ++c) acc += wr[c] * pr[c];
        sh[b][j] = fmaxf(acc, 0.0f);
    }
    __syncthreads();

    for (int i = t; i < 8 * 384; i += 256) {
        const int b = i / 384, k = i - b * 384;
        float acc = b2[k];
        const float* wr = w2 + k * 16;
        #pragma unroll
        for (int j = 0; j < 16; ++j) acc += wr[j] * sh[b][j];
        satt[i] = 1.0f / (1.0f + expf(-acc));
    }
    __syncthreads();

    // Wc[b][c][k] = a0*idg + a1*CS + a2*SX + a3*SY + a4*LAP + a5*van
    for (int i = t; i < 8 * 64 * 9; i += 256) {
        const int b = i / 576;
        const int r = i - b * 576;
        const int c = r / 9;
        const int k = r - c * 9;
        const float* ab = satt + b * 384;
        float v = ab[0 * 64 + c] * idg_w[c * 9 + k]
                + ab[1 * 64 + c] * K_CS[k]
                + ab[2 * 64 + c] * K_SX[k]
                + ab[3 * 64 + c] * K_SY[k]
                + ab[4 * 64 + c] * K_LAP[k]
                + ab[5 * 64 + c] * van_w[c * 9 + k];
        wc_out[i] = v;
    }

    // Prepack A-fragments (weights) for mfma_f32_16x16x32_bf16:
    // apk[kc][mb][lane][j] = bf16(fus_w[mb*16 + (lane&15)][kc*32 + (lane>>4)*8 + j])
    for (int i = t; i < 4096; i += 256) {
        const int j    = i & 7;
        const int lane = (i >> 3) & 63;
        const int mb   = (i >> 9) & 3;
        const int kc   = i >> 11;
        const int o = mb * 16 + (lane & 15);
        const int c = kc * 32 + (lane >> 4) * 8 + j;
        apk[i] = f2bf(fus_w[o * 64 + c]);
    }
}

// ------ Kernel C: fused depthwise(combined) conv + bf16-MFMA 1x1 conv ------
// EXACT round-10 proven kernel (best measured: 89.8us total), untouched.
__global__ __launch_bounds__(256, 3) void fused_dw_mix_kernel(
    const float* __restrict__ x,        // [8][64][256][256]
    const float* __restrict__ wc,       // [8][64][9]
    const unsigned short* __restrict__ apk, // [2][4][64][8] bf16 weight frags
    const float* __restrict__ fus_b,    // [64]
    float* __restrict__ out)            // [8][64][256][256]
{
    __shared__ unsigned short s_dw[2][32 * 256];   // 2 x 16 KB

    // bijective XCD swizzle (r7-proven): each XCD owns one batch image.
    const int bid = blockIdx.x;
    const int s   = (bid & 7) * 256 + (bid >> 3);
    const int x0  = (s & 7) * 32;
    const int y0  = ((s >> 3) & 31) * 8;
    const int b   = s >> 8;

    const int t    = threadIdx.x;
    const int l    = t & 63;
    const int wv   = t >> 6;            // 0..3 (wave-uniform)
    const int ln15 = l & 15;
    const int lh   = l >> 4;            // 0..3

    // phase-1 mapping: channel-sub q, column group g
    const int q  = l >> 3;              // 0..7
    const int g  = l & 7;               // 0..7
    const int xx = x0 + g * 4;
    const float* xb  = x + (size_t)b * (kC * kPlane);
    const float* wcb = wc + b * 576;
    const bool xlo = (xx > 0);
    const bool xhi = (xx < 252);
    const int  elo = xlo ? -1 : 0;      // in-bounds left-tap offset
    const int  ehi = xhi ?  4 : 0;      // in-bounds right-tap offset
    const int  rTop = (y0 > 0)   ? y0 - 1 : 0;     // clamped top halo row
    const int  rBot = (y0 < 248) ? y0 + 8 : 255;   // clamped bottom halo row
    const float mT  = (y0 > 0)   ? 1.0f : 0.0f;
    const float mB  = (y0 < 248) ? 1.0f : 0.0f;

    f32x4 acc[4][4];
    #pragma unroll
    for (int i = 0; i < 4; ++i)
        #pragma unroll
        for (int j = 0; j < 4; ++j) acc[i][j] = (f32x4){0.f, 0.f, 0.f, 0.f};

    auto conv_chunk = [&](int chunk, unsigned short* sbuf) {
        const int cl = wv * 8 + q;                 // cl&7 == q, cl>>3 == wv
        const int c  = chunk * 32 + cl;
        const float* wp = wcb + c * 9;             // per-lane channel weights
        const float w0 = wp[0], w1 = wp[1], w2 = wp[2];
        const float w3 = wp[3], w4 = wp[4], w5 = wp[5];
        const float w6 = wp[6], w7 = wp[7], w8 = wp[8];
        const float* xc = xb + (size_t)c * kPlane;

        float lmP, rmP; float4 MP;                 // row y-1
        float lmC, rmC; float4 MC;                 // row y
        {   // top halo row (clamped + masked)
            const float* rp = xc + rTop * kW + xx;
            MP  = *(const float4*)rp;
            lmP = xlo ? rp[elo] : 0.f;
            rmP = xhi ? rp[ehi] : 0.f;
            MP.x *= mT; MP.y *= mT; MP.z *= mT; MP.w *= mT; lmP *= mT; rmP *= mT;
        }
        {   // row y0 (always in-bounds)
            const float* rp = xc + y0 * kW + xx;
            MC  = *(const float4*)rp;
            lmC = xlo ? rp[elo] : 0.f;
            rmC = xhi ? rp[ehi] : 0.f;
        }
        #pragma unroll
        for (int y = 0; y < 8; ++y) {
            const int ry = (y < 7) ? (y0 + y + 1) : rBot;
            const float* rp = xc + ry * kW + xx;
            float4 MN  = *(const float4*)rp;
            float  lmN = xlo ? rp[elo] : 0.f;
            float  rmN = xhi ? rp[ehi] : 0.f;
            if (y == 7) { MN.x *= mB; MN.y *= mB; MN.z *= mB; MN.w *= mB; lmN *= mB; rmN *= mB; }

            const float a0 = w0 * lmP  + w1 * MP.x + w2 * MP.y
                           + w3 * lmC  + w4 * MC.x + w5 * MC.y
                           + w6 * lmN  + w7 * MN.x + w8 * MN.y;
            const float a1 = w0 * MP.x + w1 * MP.y + w2 * MP.z
                           + w3 * MC.x + w4 * MC.y + w5 * MC.z
                           + w6 * MN.x + w7 * MN.y + w8 * MN.z;
            const float a2 = w0 * MP.y + w1 * MP.z + w2 * MP.w
                           + w3 * MC.y + w4 * MC.z + w5 * MC.w
                           + w6 * MN.y + w7 * MN.z + w8 * MN.w;
            const float a3 = w0 * MP.z + w1 * MP.w + w2 * rmP
                           + w3 * MC.z + w4 * MC.w + w5 * rmC
                           + w6 * MN.z + w7 * MN.w + w8 * rmN;

            uint2 v;
            v.x = (unsigned)f2bf(a0) | ((unsigned)f2bf(a1) << 16);
            v.y = (unsigned)f2bf(a2) | ((unsigned)f2bf(a3) << 16);
            // selem(cl, y*32 + g*4)
            *(uint2*)&sbuf[cl * 256 + ((y * 32 + g * 4) ^ (q << 5) ^ (wv << 4))] = v;

            lmP = lmC; MP = MC; rmP = rmC;         // rotate window (static)
            lmC = lmN; MC = MN; rmC = rmN;
        }
    };

    auto mfma_chunk = [&](int chunk, const unsigned short* sbuf) {
        bf16x8 af[4];
        #pragma unroll
        for (int mb = 0; mb < 4; ++mb)
            af[mb] = *(const bf16x8*)(apk + (size_t)((chunk * 4 + mb) * 64 + l) * 8);
        #pragma unroll
        for (int pb = 0; pb < 4; ++pb) {
            const int p = wv * 64 + pb * 16 + ln15;
            bf16x8 bfr;
            #pragma unroll
            for (int j = 0; j < 8; ++j)
                bfr[j] = (short)sbuf[(lh * 8 + j) * 256 + (p ^ (j << 5) ^ (lh << 4))];
            #pragma unroll
            for (int mb = 0; mb < 4; ++mb)
                acc[mb][pb] = __builtin_amdgcn_mfma_f32_16x16x32_bf16(af[mb], bfr, acc[mb][pb], 0, 0, 0);
        }
    };

    conv_chunk(0, &s_dw[0][0]);
    __syncthreads();                    // buf0 ready
    conv_chunk(1, &s_dw[1][0]);         // overlaps with mfma_chunk(0)
    mfma_chunk(0, &s_dw[0][0]);
    __syncthreads();                    // buf1 ready
    mfma_chunk(1, &s_dw[1][0]);

    // ---------------- epilogue: bias + plain b32 stores ----------------
    // D layout: o = mb*16 + lh*4 + r (row), p = wv*64 + pb*16 + ln15 (col)
    float* ob = out + (size_t)(b * kC) * kPlane;
    #pragma unroll
    for (int mb = 0; mb < 4; ++mb) {
        #pragma unroll
        for (int pb = 0; pb < 4; ++pb) {
            const int p   = wv * 64 + pb * 16 + ln15;
            const int opy = p >> 5;
            const int opx = p & 31;
            float* pbp = ob + (size_t)(y0 + opy) * kW + (x0 + opx);
            #pragma unroll
            for (int r = 0; r < 4; ++r) {
                const int o = mb * 16 + lh * 4 + r;
                pbp[(size_t)o * kPlane] = acc[mb][pb][r] + fus_b[o];
            }
        }
    }
}

extern "C" void kernel_launch(void* const* d_in, const int* in_sizes, int n_in,
                              void* d_out, int out_size, void* d_ws, size_t ws_size,
                              hipStream_t stream) {
    const float* x     = (const float*)d_in[0];
    const float* idg_w = (const float*)d_in[1];
    const float* van_w = (const float*)d_in[2];
    const float* w1    = (const float*)d_in[3];
    const float* b1    = (const float*)d_in[4];
    const float* w2    = (const float*)d_in[5];
    const float* b2    = (const float*)d_in[6];
    const float* fw    = (const float*)d_in[7];
    const float* fb    = (const float*)d_in[8];
    float* out = (float*)d_out;

    float* wsf     = (float*)d_ws;
    float* partial = wsf;                                // 2048 floats
    float* wcbuf   = wsf + 2048;                         // 4608 floats
    unsigned short* apk = (unsigned short*)(wsf + 2048 + 4608); // 4096 ushort (=2048 floats)
    unsigned* counter   = (unsigned*)(wsf + 2048 + 4608 + 2048); // 1 uint

    hipMemsetAsync(counter, 0, sizeof(unsigned), stream);        // deterministic reset
    hipLaunchKernelGGL(pool_att_kernel, dim3(2048), dim3(256), 0, stream,
                       x, idg_w, van_w, w1, b1, w2, b2, fw,
                       partial, counter, wcbuf, apk);
    hipLaunchKernelGGL(fused_dw_mix_kernel, dim3(2048), dim3(256), 0, stream,
                       x, wcbuf, apk, fb, out);
}

// Round 17
// 158.502 us; speedup vs baseline: 1.0012x; 1.0012x over previous
//
#include <hip/hip_runtime.h>
#include <hip/hip_bf16.h>
#include <math.h>

// Problem constants: B=8, C=64, H=256, W=256
static constexpr int kC = 64;
static constexpr int kH = 256;
static constexpr int kW = 256;
static constexpr int kPlane = kH * kW;   // 65536

typedef __attribute__((ext_vector_type(8))) short bf16x8;
typedef __attribute__((ext_vector_type(4))) float f32x4;

__device__ __forceinline__ unsigned short f2bf(float f) {
    unsigned u = __builtin_bit_cast(unsigned, f);
    u += 0x7FFFu + ((u >> 16) & 1u);     // round-to-nearest-even
    return (unsigned short)(u >> 16);
}

// Fixed stencils (same normalization as reference)
__constant__ float K_SX[9]  = {-0.125f, 0.0f, 0.125f,  -0.25f, 0.0f, 0.25f,  -0.125f, 0.0f, 0.125f};
__constant__ float K_SY[9]  = {-0.125f, -0.25f, -0.125f,  0.0f, 0.0f, 0.0f,  0.125f, 0.25f, 0.125f};
__constant__ float K_LAP[9] = {0.0f, -1.0f/6.0f, 0.0f,  -1.0f/6.0f, 4.0f/6.0f, -1.0f/6.0f,  0.0f, -1.0f/6.0f, 0.0f};
__constant__ float K_CS[9]  = {-1.0f/9.0f, -1.0f/9.0f, -1.0f/9.0f,  -1.0f/9.0f, 8.0f/9.0f, -1.0f/9.0f,  -1.0f/9.0f, -1.0f/9.0f, -1.0f/9.0f};

// ---- Kernel A+B merged: partial pool (all blocks) + att/prepack (last block) ----
// Pool body = r10-proven. Last-finished block (device-scope counter) runs the
// r10-proven att_wc body verbatim: deterministic output (fixed-order math,
// block identity irrelevant). Counter is memset to 0 each launch.
__global__ __launch_bounds__(256) void pool_att_kernel(
    const float* __restrict__ x,        // [8][64][256][256]
    const float* __restrict__ idg_w,    // [64][9]
    const float* __restrict__ van_w,    // [64][9]
    const float* __restrict__ w1,       // [16][64]
    const float* __restrict__ b1,       // [16]
    const float* __restrict__ w2,       // [384][16]
    const float* __restrict__ b2,       // [384]
    const float* __restrict__ fus_w,    // [64][64] (o,c)
    float* __restrict__ partial,        // [512][4]
    unsigned* __restrict__ counter,     // 1 (zeroed each launch)
    float* __restrict__ wc_out,         // [8][64][9]
    unsigned short* __restrict__ apk)   // [2][4][64][8] bf16 weight fragments
{
    // ---------------- pool partial (r10 body) ----------------
    const int blk = blockIdx.x;            // 0..2047
    const int bc  = blk >> 2;
    const int q   = blk & 3;
    const float4* p = (const float4*)(x + (size_t)bc * kPlane) + q * 4096 + threadIdx.x;
    float s0 = 0.f, s1 = 0.f, s2 = 0.f, s3 = 0.f;
    #pragma unroll
    for (int i = 0; i < 16; i += 4) {
        const float4 a = p[(i + 0) * 256];
        const float4 b = p[(i + 1) * 256];
        const float4 c = p[(i + 2) * 256];
        const float4 d = p[(i + 3) * 256];
        s0 += (a.x + a.y) + (a.z + a.w);
        s1 += (b.x + b.y) + (b.z + b.w);
        s2 += (c.x + c.y) + (c.z + c.w);
        s3 += (d.x + d.y) + (d.z + d.w);
    }
    float s = (s0 + s1) + (s2 + s3);
    for (int off = 32; off; off >>= 1) s += __shfl_down(s, off);
    __shared__ float red[4];
    __shared__ int slast;
    if ((threadIdx.x & 63) == 0) red[threadIdx.x >> 6] = s;
    __syncthreads();
    if (threadIdx.x == 0) {
        partial[blk] = red[0] + red[1] + red[2] + red[3];
        __threadfence();                              // release partial[blk]
        const unsigned prev = atomicAdd(counter, 1u); // device-scope
        slast = (prev == 2047u) ? 1 : 0;
    }
    __syncthreads();
    if (!slast) return;
    __threadfence();                                  // acquire all partial[]

    // ---------------- att + prepack (r10 att_wc body, verbatim) ----------------
    __shared__ float spool[512];
    __shared__ float sh[8][16];
    __shared__ float satt[8 * 384];
    const int t = threadIdx.x;

    for (int i = t; i < 512; i += 256)
        spool[i] = (partial[4 * i] + partial[4 * i + 1] + partial[4 * i + 2] + partial[4 * i + 3])
                   * (1.0f / (float)kPlane);
    __syncthreads();

    if (t < 128) {
        const int b = t >> 4, j = t & 15;
        float acc = b1[j];
        const float* wr = w1 + j * 64;
        const float* pr = spool + b * 64;
        #pragma unroll 8
        for (int c = 0; c < 64; ++c) acc += wr[c] * pr[c];
        sh[b][j] = fmaxf(acc, 0.0f);
    }
    __syncthreads();

    for (int i = t; i < 8 * 384; i += 256) {
        const int b = i / 384, k = i - b * 384;
        float acc = b2[k];
        const float* wr = w2 + k * 16;
        #pragma unroll
        for (int j = 0; j < 16; ++j) acc += wr[j] * sh[b][j];
        satt[i] = 1.0f / (1.0f + expf(-acc));
    }
    __syncthreads();

    // Wc[b][c][k] = a0*idg + a1*CS + a2*SX + a3*SY + a4*LAP + a5*van
    for (int i = t; i < 8 * 64 * 9; i += 256) {
        const int b = i / 576;
        const int r = i - b * 576;
        const int c = r / 9;
        const int k = r - c * 9;
        const float* ab = satt + b * 384;
        float v = ab[0 * 64 + c] * idg_w[c * 9 + k]
                + ab[1 * 64 + c] * K_CS[k]
                + ab[2 * 64 + c] * K_SX[k]
                + ab[3 * 64 + c] * K_SY[k]
                + ab[4 * 64 + c] * K_LAP[k]
                + ab[5 * 64 + c] * van_w[c * 9 + k];
        wc_out[i] = v;
    }

    // Prepack A-fragments (weights) for mfma_f32_16x16x32_bf16:
    // apk[kc][mb][lane][j] = bf16(fus_w[mb*16 + (lane&15)][kc*32 + (lane>>4)*8 + j])
    for (int i = t; i < 4096; i += 256) {
        const int j    = i & 7;
        const int lane = (i >> 3) & 63;
        const int mb   = (i >> 9) & 3;
        const int kc   = i >> 11;
        const int o = mb * 16 + (lane & 15);
        const int c = kc * 32 + (lane >> 4) * 8 + j;
        apk[i] = f2bf(fus_w[o * 64 + c]);
    }
}

// ------ Kernel C: fused depthwise(combined) conv + bf16-MFMA 1x1 conv ------
// EXACT round-10 proven kernel (best measured: 89.8us total), untouched.
__global__ __launch_bounds__(256, 3) void fused_dw_mix_kernel(
    const float* __restrict__ x,        // [8][64][256][256]
    const float* __restrict__ wc,       // [8][64][9]
    const unsigned short* __restrict__ apk, // [2][4][64][8] bf16 weight frags
    const float* __restrict__ fus_b,    // [64]
    float* __restrict__ out)            // [8][64][256][256]
{
    __shared__ unsigned short s_dw[2][32 * 256];   // 2 x 16 KB

    // bijective XCD swizzle (r7-proven): each XCD owns one batch image.
    const int bid = blockIdx.x;
    const int s   = (bid & 7) * 256 + (bid >> 3);
    const int x0  = (s & 7) * 32;
    const int y0  = ((s >> 3) & 31) * 8;
    const int b   = s >> 8;

    const int t    = threadIdx.x;
    const int l    = t & 63;
    const int wv   = t >> 6;            // 0..3 (wave-uniform)
    const int ln15 = l & 15;
    const int lh   = l >> 4;            // 0..3

    // phase-1 mapping: channel-sub q, column group g
    const int q  = l >> 3;              // 0..7
    const int g  = l & 7;               // 0..7
    const int xx = x0 + g * 4;
    const float* xb  = x + (size_t)b * (kC * kPlane);
    const float* wcb = wc + b * 576;
    const bool xlo = (xx > 0);
    const bool xhi = (xx < 252);
    const int  elo = xlo ? -1 : 0;      // in-bounds left-tap offset
    const int  ehi = xhi ?  4 : 0;      // in-bounds right-tap offset
    const int  rTop = (y0 > 0)   ? y0 - 1 : 0;     // clamped top halo row
    const int  rBot = (y0 < 248) ? y0 + 8 : 255;   // clamped bottom halo row
    const float mT  = (y0 > 0)   ? 1.0f : 0.0f;
    const float mB  = (y0 < 248) ? 1.0f : 0.0f;

    f32x4 acc[4][4];
    #pragma unroll
    for (int i = 0; i < 4; ++i)
        #pragma unroll
        for (int j = 0; j < 4; ++j) acc[i][j] = (f32x4){0.f, 0.f, 0.f, 0.f};

    auto conv_chunk = [&](int chunk, unsigned short* sbuf) {
        const int cl = wv * 8 + q;                 // cl&7 == q, cl>>3 == wv
        const int c  = chunk * 32 + cl;
        const float* wp = wcb + c * 9;             // per-lane channel weights
        const float w0 = wp[0], w1 = wp[1], w2 = wp[2];
        const float w3 = wp[3], w4 = wp[4], w5 = wp[5];
        const float w6 = wp[6], w7 = wp[7], w8 = wp[8];
        const float* xc = xb + (size_t)c * kPlane;

        float lmP, rmP; float4 MP;                 // row y-1
        float lmC, rmC; float4 MC;                 // row y
        {   // top halo row (clamped + masked)
            const float* rp = xc + rTop * kW + xx;
            MP  = *(const float4*)rp;
            lmP = xlo ? rp[elo] : 0.f;
            rmP = xhi ? rp[ehi] : 0.f;
            MP.x *= mT; MP.y *= mT; MP.z *= mT; MP.w *= mT; lmP *= mT; rmP *= mT;
        }
        {   // row y0 (always in-bounds)
            const float* rp = xc + y0 * kW + xx;
            MC  = *(const float4*)rp;
            lmC = xlo ? rp[elo] : 0.f;
            rmC = xhi ? rp[ehi] : 0.f;
        }
        #pragma unroll
        for (int y = 0; y < 8; ++y) {
            const int ry = (y < 7) ? (y0 + y + 1) : rBot;
            const float* rp = xc + ry * kW + xx;
            float4 MN  = *(const float4*)rp;
            float  lmN = xlo ? rp[elo] : 0.f;
            float  rmN = xhi ? rp[ehi] : 0.f;
            if (y == 7) { MN.x *= mB; MN.y *= mB; MN.z *= mB; MN.w *= mB; lmN *= mB; rmN *= mB; }

            const float a0 = w0 * lmP  + w1 * MP.x + w2 * MP.y
                           + w3 * lmC  + w4 * MC.x + w5 * MC.y
                           + w6 * lmN  + w7 * MN.x + w8 * MN.y;
            const float a1 = w0 * MP.x + w1 * MP.y + w2 * MP.z
                           + w3 * MC.x + w4 * MC.y + w5 * MC.z
                           + w6 * MN.x + w7 * MN.y + w8 * MN.z;
            const float a2 = w0 * MP.y + w1 * MP.z + w2 * MP.w
                           + w3 * MC.y + w4 * MC.z + w5 * MC.w
                           + w6 * MN.y + w7 * MN.z + w8 * MN.w;
            const float a3 = w0 * MP.z + w1 * MP.w + w2 * rmP
                           + w3 * MC.z + w4 * MC.w + w5 * rmC
                           + w6 * MN.z + w7 * MN.w + w8 * rmN;

            uint2 v;
            v.x = (unsigned)f2bf(a0) | ((unsigned)f2bf(a1) << 16);
            v.y = (unsigned)f2bf(a2) | ((unsigned)f2bf(a3) << 16);
            // selem(cl, y*32 + g*4)
            *(uint2*)&sbuf[cl * 256 + ((y * 32 + g * 4) ^ (q << 5) ^ (wv << 4))] = v;

            lmP = lmC; MP = MC; rmP = rmC;         // rotate window (static)
            lmC = lmN; MC = MN; rmC = rmN;
        }
    };

    auto mfma_chunk = [&](int chunk, const unsigned short* sbuf) {
        bf16x8 af[4];
        #pragma unroll
        for (int mb = 0; mb < 4; ++mb)
            af[mb] = *(const bf16x8*)(apk + (size_t)((chunk * 4 + mb) * 64 + l) * 8);
        #pragma unroll
        for (int pb = 0; pb < 4; ++pb) {
            const int p = wv * 64 + pb * 16 + ln15;
            bf16x8 bfr;
            #pragma unroll
            for (int j = 0; j < 8; ++j)
                bfr[j] = (short)sbuf[(lh * 8 + j) * 256 + (p ^ (j << 5) ^ (lh << 4))];
            #pragma unroll
            for (int mb = 0; mb < 4; ++mb)
                acc[mb][pb] = __builtin_amdgcn_mfma_f32_16x16x32_bf16(af[mb], bfr, acc[mb][pb], 0, 0, 0);
        }
    };

    conv_chunk(0, &s_dw[0][0]);
    __syncthreads();                    // buf0 ready
    conv_chunk(1, &s_dw[1][0]);         // overlaps with mfma_chunk(0)
    mfma_chunk(0, &s_dw[0][0]);
    __syncthreads();                    // buf1 ready
    mfma_chunk(1, &s_dw[1][0]);

    // ---------------- epilogue: bias + plain b32 stores ----------------
    // D layout: o = mb*16 + lh*4 + r (row), p = wv*64 + pb*16 + ln15 (col)
    float* ob = out + (size_t)(b * kC) * kPlane;
    #pragma unroll
    for (int mb = 0; mb < 4; ++mb) {
        #pragma unroll
        for (int pb = 0; pb < 4; ++pb) {
            const int p   = wv * 64 + pb * 16 + ln15;
            const int opy = p >> 5;
            const int opx = p & 31;
            float* pbp = ob + (size_t)(y0 + opy) * kW + (x0 + opx);
            #pragma unroll
            for (int r = 0; r < 4; ++r) {
                const int o = mb * 16 + lh * 4 + r;
                pbp[(size_t)o * kPlane] = acc[mb][pb][r] + fus_b[o];
            }
        }
    }
}

extern "C" void kernel_launch(void* const* d_in, const int* in_sizes, int n_in,
                              void* d_out, int out_size, void* d_ws, size_t ws_size,
                              hipStream_t stream) {
    const float* x     = (const float*)d_in[0];
    const float* idg_w = (const float*)d_in[1];
    const float* van_w = (const float*)d_in[2];
    const float* w1    = (const float*)d_in[3];
    const float* b1    = (const float*)d_in[4];
    const float* w2    = (const float*)d_in[5];
    const float* b2    = (const float*)d_in[6];
    const float* fw    = (const float*)d_in[7];
    const float* fb    = (const float*)d_in[8];
    float* out = (float*)d_out;

    float* wsf     = (float*)d_ws;
    float* partial = wsf;                                // 2048 floats
    float* wcbuf   = wsf + 2048;                         // 4608 floats
    unsigned short* apk = (unsigned short*)(wsf + 2048 + 4608); // 4096 ushort (=2048 floats)
    unsigned* counter   = (unsigned*)(wsf + 2048 + 4608 + 2048); // 1 uint

    hipMemsetAsync(counter, 0, sizeof(unsigned), stream);        // deterministic reset
    hipLaunchKernelGGL(pool_att_kernel, dim3(2048), dim3(256), 0, stream,
                       x, idg_w, van_w, w1, b1, w2, b2, fw,
                       partial, counter, wcbuf, apk);
    hipLaunchKernelGGL(fused_dw_mix_kernel, dim3(2048), dim3(256), 0, stream,
                       x, wcbuf, apk, fb, out);
}

// Round 18
// 89.742 us; speedup vs baseline: 1.7683x; 1.7662x over previous
//
#include <hip/hip_runtime.h>
#include <hip/hip_bf16.h>
#include <math.h>

// Problem constants: B=8, C=64, H=256, W=256
static constexpr int kC = 64;
static constexpr int kH = 256;
static constexpr int kW = 256;
static constexpr int kPlane = kH * kW;   // 65536

typedef __attribute__((ext_vector_type(8))) short bf16x8;
typedef __attribute__((ext_vector_type(4))) float f32x4;

__device__ __forceinline__ unsigned short f2bf(float f) {
    unsigned u = __builtin_bit_cast(unsigned, f);
    u += 0x7FFFu + ((u >> 16) & 1u);     // round-to-nearest-even
    return (unsigned short)(u >> 16);
}

// Fixed stencils (same normalization as reference)
__constant__ float K_SX[9]  = {-0.125f, 0.0f, 0.125f,  -0.25f, 0.0f, 0.25f,  -0.125f, 0.0f, 0.125f};
__constant__ float K_SY[9]  = {-0.125f, -0.25f, -0.125f,  0.0f, 0.0f, 0.0f,  0.125f, 0.25f, 0.125f};
__constant__ float K_LAP[9] = {0.0f, -1.0f/6.0f, 0.0f,  -1.0f/6.0f, 4.0f/6.0f, -1.0f/6.0f,  0.0f, -1.0f/6.0f, 0.0f};
__constant__ float K_CS[9]  = {-1.0f/9.0f, -1.0f/9.0f, -1.0f/9.0f,  -1.0f/9.0f, 8.0f/9.0f, -1.0f/9.0f,  -1.0f/9.0f, -1.0f/9.0f, -1.0f/9.0f};

// -------- Kernel A: partial global-average-pool (4 blocks per plane) --------
__global__ __launch_bounds__(256) void pool_kernel(const float* __restrict__ x,
                                                   float* __restrict__ partial) {
    const int blk = blockIdx.x;            // 0..2047
    const int bc  = blk >> 2;
    const int q   = blk & 3;
    const float4* p = (const float4*)(x + (size_t)bc * kPlane) + q * 4096 + threadIdx.x;
    float s0 = 0.f, s1 = 0.f, s2 = 0.f, s3 = 0.f;
    #pragma unroll
    for (int i = 0; i < 16; i += 4) {
        const float4 a = p[(i + 0) * 256];
        const float4 b = p[(i + 1) * 256];
        const float4 c = p[(i + 2) * 256];
        const float4 d = p[(i + 3) * 256];
        s0 += (a.x + a.y) + (a.z + a.w);
        s1 += (b.x + b.y) + (b.z + b.w);
        s2 += (c.x + c.y) + (c.z + c.w);
        s3 += (d.x + d.y) + (d.z + d.w);
    }
    float s = (s0 + s1) + (s2 + s3);
    for (int off = 32; off; off >>= 1) s += __shfl_down(s, off);
    __shared__ float red[4];
    if ((threadIdx.x & 63) == 0) red[threadIdx.x >> 6] = s;
    __syncthreads();
    if (threadIdx.x == 0) partial[blk] = red[0] + red[1] + red[2] + red[3];
}

// -- Kernel B: SE MLP + combined 3x3 kernels + MFMA A-fragment prepack ----
// (exact round-7/9/10 version: single block, proven)
__global__ __launch_bounds__(256) void att_wc_kernel(
    const float* __restrict__ partial,  // [512][4]
    const float* __restrict__ idg_w,    // [64][9]
    const float* __restrict__ van_w,    // [64][9]
    const float* __restrict__ w1,       // [16][64]
    const float* __restrict__ b1,       // [16]
    const float* __restrict__ w2,       // [384][16]
    const float* __restrict__ b2,       // [384]
    const float* __restrict__ fus_w,    // [64][64] (o,c)
    float* __restrict__ wc_out,         // [8][64][9]
    unsigned short* __restrict__ apk)   // [2][4][64][8] bf16 weight fragments
{
    __shared__ float spool[512];
    __shared__ float sh[8][16];
    __shared__ float satt[8 * 384];
    const int t = threadIdx.x;

    for (int i = t; i < 512; i += 256)
        spool[i] = (partial[4 * i] + partial[4 * i + 1] + partial[4 * i + 2] + partial[4 * i + 3])
                   * (1.0f / (float)kPlane);
    __syncthreads();

    if (t < 128) {
        const int b = t >> 4, j = t & 15;
        float acc = b1[j];
        const float* wr = w1 + j * 64;
        const float* pr = spool + b * 64;
        #pragma unroll 8
        for (int c = 0; c < 64; ++c) acc += wr[c] * pr[c];
        sh[b][j] = fmaxf(acc, 0.0f);
    }
    __syncthreads();

    for (int i = t; i < 8 * 384; i += 256) {
        const int b = i / 384, k = i - b * 384;
        float acc = b2[k];
        const float* wr = w2 + k * 16;
        #pragma unroll
        for (int j = 0; j < 16; ++j) acc += wr[j] * sh[b][j];
        satt[i] = 1.0f / (1.0f + expf(-acc));
    }
    __syncthreads();

    // Wc[b][c][k] = a0*idg + a1*CS + a2*SX + a3*SY + a4*LAP + a5*van
    for (int i = t; i < 8 * 64 * 9; i += 256) {
        const int b = i / 576;
        const int r = i - b * 576;
        const int c = r / 9;
        const int k = r - c * 9;
        const float* ab = satt + b * 384;
        float v = ab[0 * 64 + c] * idg_w[c * 9 + k]
                + ab[1 * 64 + c] * K_CS[k]
                + ab[2 * 64 + c] * K_SX[k]
                + ab[3 * 64 + c] * K_SY[k]
                + ab[4 * 64 + c] * K_LAP[k]
                + ab[5 * 64 + c] * van_w[c * 9 + k];
        wc_out[i] = v;
    }

    // Prepack A-fragments (weights) for mfma_f32_16x16x32_bf16:
    // apk[kc][mb][lane][j] = bf16(fus_w[mb*16 + (lane&15)][kc*32 + (lane>>4)*8 + j])
    for (int i = t; i < 4096; i += 256) {
        const int j    = i & 7;
        const int lane = (i >> 3) & 63;
        const int mb   = (i >> 9) & 3;
        const int kc   = i >> 11;
        const int o = mb * 16 + (lane & 15);
        const int c = kc * 32 + (lane >> 4) * 8 + j;
        apk[i] = f2bf(fus_w[o * 64 + c]);
    }
}

// ------ Kernel C: fused depthwise(combined) conv + bf16-MFMA 1x1 conv ------
// EXACT round-10 proven kernel (best measured: 89.8us total):
// rolling-window phase 1 (each input row loaded once), double-buffered
// bf16 LDS with conv(c1) overlapping mfma(c0), XOR swizzle, plain stores,
// XCD-bijective block swizzle at grid 2048, __launch_bounds__(256,3).
__global__ __launch_bounds__(256, 3) void fused_dw_mix_kernel(
    const float* __restrict__ x,        // [8][64][256][256]
    const float* __restrict__ wc,       // [8][64][9]
    const unsigned short* __restrict__ apk, // [2][4][64][8] bf16 weight frags
    const float* __restrict__ fus_b,    // [64]
    float* __restrict__ out)            // [8][64][256][256]
{
    __shared__ unsigned short s_dw[2][32 * 256];   // 2 x 16 KB

    // bijective XCD swizzle (r7-proven): each XCD owns one batch image.
    const int bid = blockIdx.x;
    const int s   = (bid & 7) * 256 + (bid >> 3);
    const int x0  = (s & 7) * 32;
    const int y0  = ((s >> 3) & 31) * 8;
    const int b   = s >> 8;

    const int t    = threadIdx.x;
    const int l    = t & 63;
    const int wv   = t >> 6;            // 0..3 (wave-uniform)
    const int ln15 = l & 15;
    const int lh   = l >> 4;            // 0..3

    // phase-1 mapping: channel-sub q, column group g
    const int q  = l >> 3;              // 0..7
    const int g  = l & 7;               // 0..7
    const int xx = x0 + g * 4;
    const float* xb  = x + (size_t)b * (kC * kPlane);
    const float* wcb = wc + b * 576;
    const bool xlo = (xx > 0);
    const bool xhi = (xx < 252);
    const int  elo = xlo ? -1 : 0;      // in-bounds left-tap offset
    const int  ehi = xhi ?  4 : 0;      // in-bounds right-tap offset
    const int  rTop = (y0 > 0)   ? y0 - 1 : 0;     // clamped top halo row
    const int  rBot = (y0 < 248) ? y0 + 8 : 255;   // clamped bottom halo row
    const float mT  = (y0 > 0)   ? 1.0f : 0.0f;
    const float mB  = (y0 < 248) ? 1.0f : 0.0f;

    f32x4 acc[4][4];
    #pragma unroll
    for (int i = 0; i < 4; ++i)
        #pragma unroll
        for (int j = 0; j < 4; ++j) acc[i][j] = (f32x4){0.f, 0.f, 0.f, 0.f};

    auto conv_chunk = [&](int chunk, unsigned short* sbuf) {
        const int cl = wv * 8 + q;                 // cl&7 == q, cl>>3 == wv
        const int c  = chunk * 32 + cl;
        const float* wp = wcb + c * 9;             // per-lane channel weights
        const float w0 = wp[0], w1 = wp[1], w2 = wp[2];
        const float w3 = wp[3], w4 = wp[4], w5 = wp[5];
        const float w6 = wp[6], w7 = wp[7], w8 = wp[8];
        const float* xc = xb + (size_t)c * kPlane;

        float lmP, rmP; float4 MP;                 // row y-1
        float lmC, rmC; float4 MC;                 // row y
        {   // top halo row (clamped + masked)
            const float* rp = xc + rTop * kW + xx;
            MP  = *(const float4*)rp;
            lmP = xlo ? rp[elo] : 0.f;
            rmP = xhi ? rp[ehi] : 0.f;
            MP.x *= mT; MP.y *= mT; MP.z *= mT; MP.w *= mT; lmP *= mT; rmP *= mT;
        }
        {   // row y0 (always in-bounds)
            const float* rp = xc + y0 * kW + xx;
            MC  = *(const float4*)rp;
            lmC = xlo ? rp[elo] : 0.f;
            rmC = xhi ? rp[ehi] : 0.f;
        }
        #pragma unroll
        for (int y = 0; y < 8; ++y) {
            const int ry = (y < 7) ? (y0 + y + 1) : rBot;
            const float* rp = xc + ry * kW + xx;
            float4 MN  = *(const float4*)rp;
            float  lmN = xlo ? rp[elo] : 0.f;
            float  rmN = xhi ? rp[ehi] : 0.f;
            if (y == 7) { MN.x *= mB; MN.y *= mB; MN.z *= mB; MN.w *= mB; lmN *= mB; rmN *= mB; }

            const float a0 = w0 * lmP  + w1 * MP.x + w2 * MP.y
                           + w3 * lmC  + w4 * MC.x + w5 * MC.y
                           + w6 * lmN  + w7 * MN.x + w8 * MN.y;
            const float a1 = w0 * MP.x + w1 * MP.y + w2 * MP.z
                           + w3 * MC.x + w4 * MC.y + w5 * MC.z
                           + w6 * MN.x + w7 * MN.y + w8 * MN.z;
            const float a2 = w0 * MP.y + w1 * MP.z + w2 * MP.w
                           + w3 * MC.y + w4 * MC.z + w5 * MC.w
                           + w6 * MN.y + w7 * MN.z + w8 * MN.w;
            const float a3 = w0 * MP.z + w1 * MP.w + w2 * rmP
                           + w3 * MC.z + w4 * MC.w + w5 * rmC
                           + w6 * MN.z + w7 * MN.w + w8 * rmN;

            uint2 v;
            v.x = (unsigned)f2bf(a0) | ((unsigned)f2bf(a1) << 16);
            v.y = (unsigned)f2bf(a2) | ((unsigned)f2bf(a3) << 16);
            // selem(cl, y*32 + g*4)
            *(uint2*)&sbuf[cl * 256 + ((y * 32 + g * 4) ^ (q << 5) ^ (wv << 4))] = v;

            lmP = lmC; MP = MC; rmP = rmC;         // rotate window (static)
            lmC = lmN; MC = MN; rmC = rmN;
        }
    };

    auto mfma_chunk = [&](int chunk, const unsigned short* sbuf) {
        bf16x8 af[4];
        #pragma unroll
        for (int mb = 0; mb < 4; ++mb)
            af[mb] = *(const bf16x8*)(apk + (size_t)((chunk * 4 + mb) * 64 + l) * 8);
        #pragma unroll
        for (int pb = 0; pb < 4; ++pb) {
            const int p = wv * 64 + pb * 16 + ln15;
            bf16x8 bfr;
            #pragma unroll
            for (int j = 0; j < 8; ++j)
                bfr[j] = (short)sbuf[(lh * 8 + j) * 256 + (p ^ (j << 5) ^ (lh << 4))];
            #pragma unroll
            for (int mb = 0; mb < 4; ++mb)
                acc[mb][pb] = __builtin_amdgcn_mfma_f32_16x16x32_bf16(af[mb], bfr, acc[mb][pb], 0, 0, 0);
        }
    };

    conv_chunk(0, &s_dw[0][0]);
    __syncthreads();                    // buf0 ready
    conv_chunk(1, &s_dw[1][0]);         // overlaps with mfma_chunk(0)
    mfma_chunk(0, &s_dw[0][0]);
    __syncthreads();                    // buf1 ready
    mfma_chunk(1, &s_dw[1][0]);

    // ---------------- epilogue: bias + plain b32 stores ----------------
    // D layout: o = mb*16 + lh*4 + r (row), p = wv*64 + pb*16 + ln15 (col)
    float* ob = out + (size_t)(b * kC) * kPlane;
    #pragma unroll
    for (int mb = 0; mb < 4; ++mb) {
        #pragma unroll
        for (int pb = 0; pb < 4; ++pb) {
            const int p   = wv * 64 + pb * 16 + ln15;
            const int opy = p >> 5;
            const int opx = p & 31;
            float* pbp = ob + (size_t)(y0 + opy) * kW + (x0 + opx);
            #pragma unroll
            for (int r = 0; r < 4; ++r) {
                const int o = mb * 16 + lh * 4 + r;
                pbp[(size_t)o * kPlane] = acc[mb][pb][r] + fus_b[o];
            }
        }
    }
}

extern "C" void kernel_launch(void* const* d_in, const int* in_sizes, int n_in,
                              void* d_out, int out_size, void* d_ws, size_t ws_size,
                              hipStream_t stream) {
    const float* x     = (const float*)d_in[0];
    const float* idg_w = (const float*)d_in[1];
    const float* van_w = (const float*)d_in[2];
    const float* w1    = (const float*)d_in[3];
    const float* b1    = (const float*)d_in[4];
    const float* w2    = (const float*)d_in[5];
    const float* b2    = (const float*)d_in[6];
    const float* fw    = (const float*)d_in[7];
    const float* fb    = (const float*)d_in[8];
    float* out = (float*)d_out;

    float* wsf     = (float*)d_ws;
    float* partial = wsf;               // 2048 floats
    float* wcbuf   = wsf + 2048;        // 4608 floats
    unsigned short* apk = (unsigned short*)(wsf + 2048 + 4608); // 4096 ushort

    hipLaunchKernelGGL(pool_kernel, dim3(2048), dim3(256), 0, stream, x, partial);
    hipLaunchKernelGGL(att_wc_kernel, dim3(1), dim3(256), 0, stream,
                       partial, idg_w, van_w, w1, b1, w2, b2, fw, wcbuf, apk);
    hipLaunchKernelGGL(fused_dw_mix_kernel, dim3(2048), dim3(256), 0, stream,
                       x, wcbuf, apk, fb, out);
}